// Round 14
// baseline (422.309 us; speedup 1.0000x reference)
//
#include <hip/hip_runtime.h>
#include <hip/hip_bf16.h>
#include <stdint.h>

typedef __bf16 bf16_t;
typedef __bf16 bf16x8 __attribute__((ext_vector_type(8)));
typedef __bf16 bf16x4v __attribute__((ext_vector_type(4)));
typedef float f32x4 __attribute__((ext_vector_type(4)));

#define DEV __device__ __forceinline__

static constexpr int B_ = 2, S_ = 4096, E_ = 768, H_ = 12, D_ = 64;
static constexpr int WINDOW_ = 128;
static constexpr float QSCALE = 0.125f * 1.44269504088896f;  // fold log2(e): softmax via exp2

template<int C> struct IC { static constexpr int v = C; };

// fast exp2: single v_exp_f32 (1-ulp; flushes large-negative to 0)
DEV float fexp2(float x) { return __builtin_amdgcn_exp2f(x); }

// ---------- async 16B global -> LDS ----------
DEV void gload_lds16(const void* g, void* l) {
    __builtin_amdgcn_global_load_lds(
        (const __attribute__((address_space(1))) uint32_t*)g,
        (__attribute__((address_space(3))) uint32_t*)l, 16, 0, 0);
}

// ---------- fp32 -> bf16 convert ----------
__global__ void k_cvt(const float* __restrict__ in, bf16_t* __restrict__ out, int n) {
    int i = (blockIdx.x * blockDim.x + threadIdx.x) * 4;
    if (i < n) {
        float4 v = *(const float4*)(in + i);
        bf16x4v o;
        o[0] = (bf16_t)v.x; o[1] = (bf16_t)v.y; o[2] = (bf16_t)v.z; o[3] = (bf16_t)v.w;
        *(bf16x4v*)(out + i) = o;
    }
}

// ---------- NT GEMM: C[m][n] = sum_k A[m][k] * Bw[n][k] + bias[n] ----------
// EPI 0: q (scaled, exp2-domain) / k into [B,H,S,D]; v into vt [B,H,D,S] with keys
//        pre-permuted within 32-groups to match the PV A-fragment slot order.
// EPI 1: fp32 output [M][N]
template<int EPI>
__global__ void k_gemm(const bf16_t* __restrict__ A, const bf16_t* __restrict__ Bw,
                       const float* __restrict__ bias,
                       bf16_t* __restrict__ qb, bf16_t* __restrict__ kb, bf16_t* __restrict__ vtb,
                       float* __restrict__ outf,
                       int M, int N, int K, int mtiles) {
    __shared__ bf16_t As[128 * 64];
    __shared__ bf16_t Bs[128 * 64];
    int bid = blockIdx.x;
    int tm = bid % mtiles, tn = bid / mtiles;
    int m0 = tm * 128, n0 = tn * 128;
    int t = threadIdx.x;
    int lane = t & 63, wid = t >> 6;
    int l15 = lane & 15, l4 = lane >> 4;
    int wm = (wid & 1) * 64, wn = (wid >> 1) * 64;

    f32x4 acc[4][4];
#pragma unroll
    for (int i = 0; i < 4; ++i)
#pragma unroll
        for (int j = 0; j < 4; ++j) acc[i][j] = f32x4{0.f, 0.f, 0.f, 0.f};

    for (int kt = 0; kt < K; kt += 64) {
        __syncthreads();
#pragma unroll
        for (int c = 0; c < 4; ++c) {
            int idx = t + 256 * c;
            int row = idx >> 3, part = idx & 7;
            int kc = 8 * (part ^ (row & 7));
            gload_lds16(A + (long)(m0 + row) * K + kt + kc, (char*)As + idx * 16);
            gload_lds16(Bw + (long)(n0 + row) * K + kt + kc, (char*)Bs + idx * 16);
        }
        __syncthreads();
#pragma unroll
        for (int kk = 0; kk < 2; ++kk) {
            bf16x8 af[4], bfr[4];
#pragma unroll
            for (int i = 0; i < 4; ++i) {
                int row = wm + i * 16 + l15;
                int off = row * 128 + ((16 * (kk * 4 + l4)) ^ ((row & 7) << 4));
                af[i] = *(const bf16x8*)((const char*)As + off);
                int rowb = wn + i * 16 + l15;
                int offb = rowb * 128 + ((16 * (kk * 4 + l4)) ^ ((rowb & 7) << 4));
                bfr[i] = *(const bf16x8*)((const char*)Bs + offb);
            }
#pragma unroll
            for (int i = 0; i < 4; ++i)
#pragma unroll
                for (int j = 0; j < 4; ++j)
                    acc[i][j] = __builtin_amdgcn_mfma_f32_16x16x32_bf16(af[i], bfr[j], acc[i][j], 0, 0, 0);
        }
    }

#pragma unroll
    for (int i = 0; i < 4; ++i) {
#pragma unroll
        for (int j = 0; j < 4; ++j) {
            int n = n0 + wn + j * 16 + l15;
            float bv = bias[n];
            int mbase = m0 + wm + i * 16 + l4 * 4;
            if (EPI == 0) {
                int sel = n / 768, nn = n % 768;
                int h = nn >> 6, d = nn & 63;
                int b = mbase >> 12, s = mbase & 4095;
                if (sel == 2) {
                    bf16x4v pk;
#pragma unroll
                    for (int r = 0; r < 4; ++r) pk[r] = (bf16_t)(acc[i][j][r] + bv);
                    // permuted position: slot(8a+j)<-key(4a+j), slot(8a+4+j)<-key(16+4a+j)
                    int pos = (s & ~31) | (((s >> 2) & 3) << 3) | (((s >> 4) & 1) << 2);
                    *(bf16x4v*)(vtb + ((long)(b * H_ + h) * D_ + d) * S_ + pos) = pk;
                } else {
                    long o = ((long)(b * H_ + h) * S_ + s) * D_ + d;
#pragma unroll
                    for (int r = 0; r < 4; ++r) {
                        float v = acc[i][j][r] + bv;
                        if (sel == 0) qb[o + (long)r * D_] = (bf16_t)(v * QSCALE);
                        else          kb[o + (long)r * D_] = (bf16_t)v;
                    }
                }
            } else {
#pragma unroll
                for (int r = 0; r < 4; ++r)
                    outf[(long)(mbase + r) * 768 + n] = acc[i][j][r] + bv;
            }
        }
    }
}

// ---------- attention partials: split-K, 2 streams of 31 K-tiles ----------
// 4 waves x 32 q (two 16-row halves sharing every K/V LDS read), KVBLK=64,
// double-buffered K/V (trailing barrier = provably race-free), frozen-m per stream,
// -m folded into QK MFMA C-init, mfma row-sum. Partial o (bf16) + osum/m (f32) to ws.
__global__ __launch_bounds__(256, 5)
void k_attn_part(const bf16_t* __restrict__ q, const bf16_t* __restrict__ k,
                 const bf16_t* __restrict__ vt,
                 bf16_t* __restrict__ p0, bf16_t* __restrict__ p1,
                 float* __restrict__ sums) {
    __shared__ bf16_t Ksh[2][4096];   // [key][d], 128B rows, 3-bit chunk XOR
    __shared__ bf16_t Vsh[2][4096];   // [d][pos], 128B rows, 3-bit chunk XOR
    int raw = blockIdx.x;
    int sw_ = (raw & 7) * 192 + (raw >> 3);   // XCD-aware swizzle (1536 = 8*192)
    int strm = sw_ & 1;
    int id = sw_ >> 1;
    int bh = id >> 5, qt = id & 31;
    int q0 = qt * 128;
    int t = threadIdx.x, lane = t & 63, wid = t >> 6;
    int l15 = lane & 15, l4 = lane >> 4;

    const bf16_t* qp = q + (long)bh * S_ * D_;
    const bf16_t* kp = k + (long)bh * S_ * D_;
    const bf16_t* vp = vt + (long)bh * D_ * S_;
    bf16_t* po = strm ? p1 : p0;
    int soff = strm * (24 * S_) + bh * S_;
    int wq = q0 + wid * 32;              // this wave's 32 q-rows (2 halves of 16)

    // Q fragments per half (B-operand: col=q=l15, contraction d-chunk 8*l4)
    bf16x8 qf[2][2];
#pragma unroll
    for (int g = 0; g < 2; ++g) {
        int row = wq + g * 16 + l15;
        qf[g][0] = *(const bf16x8*)(qp + (long)row * 64 + 8 * l4);
        qf[g][1] = *(const bf16x8*)(qp + (long)row * 64 + 32 + 8 * l4);
    }

    // LDS fragment addressing: 2 VGPR bases + compile-time immediates
    int sw = (l15 & 7) << 4;
    int a0 = l15 * 128 + ((16 * l4) ^ sw);
    int a1 = a0 ^ 64;

    f32x4 o[2][4], osum[2];
    f32x4 mneg4[2];
#pragma unroll
    for (int g = 0; g < 2; ++g) {
        osum[g] = f32x4{0.f, 0.f, 0.f, 0.f};
        mneg4[g] = f32x4{0.f, 0.f, 0.f, 0.f};
#pragma unroll
        for (int ns = 0; ns < 4; ++ns) o[g][ns] = f32x4{0.f, 0.f, 0.f, 0.f};
    }

    bf16x8 onesB;
#pragma unroll
    for (int j = 0; j < 8; ++j) onesB[j] = (bf16_t)1.0f;

    // staging: 256 threads x (2 K-chunks + 2 V-chunks); linear LDS dest, pre-swizzled src
    int i2b = t + 256;
    int rowA = t >> 3, rowB = i2b >> 3;
    int part = t & 7;
    int koffA = rowA * 64 + 8 * (part ^ (rowA & 7));
    int koffB = rowB * 64 + 8 * (part ^ (rowB & 7));
    int voffA = rowA * S_ + 8 * (part ^ (rowA & 7));
    int voffB = rowB * S_ + 8 * (part ^ (rowB & 7));
    int qt2 = 2 * qt;
    int qg0 = wq + l15;       // g=0 q-row of this lane
    int qg1 = qg0 + 16;       // g=1
    int tbase = strm * 31;    // this stream's tile range: tbase..tbase+30

    auto NK = [&](int i) { return i < qt2 ? i : i + 2; };

    auto STAGE = [&](int kts, auto bufc) {
        constexpr int buf = decltype(bufc)::v;
        char* Kd = (char*)Ksh + buf * 8192 + t * 16;
        char* Vd = (char*)Vsh + buf * 8192 + t * 16;
        long ko = (long)kts << 12;
        int vo = kts << 6;
        gload_lds16(kp + ko + koffA, Kd);
        gload_lds16(kp + ko + koffB, Kd + 4096);
        gload_lds16(vp + vo + voffA, Vd);
        gload_lds16(vp + vo + voffB, Vd + 4096);
    };

    // QK for both halves, each K fragment read ONCE
    auto QK = [&](auto curc, f32x4 (*s)[4], f32x4 ci0, f32x4 ci1) {
        constexpr int cur = decltype(curc)::v;
        const char* KL = (const char*)Ksh + cur * 8192;
#pragma unroll
        for (int ks = 0; ks < 4; ++ks) {
            bf16x8 kf0 = *(const bf16x8*)(KL + a0 + ks * 2048);
            bf16x8 kf1 = *(const bf16x8*)(KL + a1 + ks * 2048);
            s[0][ks] = __builtin_amdgcn_mfma_f32_16x16x32_bf16(kf0, qf[0][0], ci0, 0, 0, 0);
            s[1][ks] = __builtin_amdgcn_mfma_f32_16x16x32_bf16(kf0, qf[1][0], ci1, 0, 0, 0);
            s[0][ks] = __builtin_amdgcn_mfma_f32_16x16x32_bf16(kf1, qf[0][1], s[0][ks], 0, 0, 0);
            s[1][ks] = __builtin_amdgcn_mfma_f32_16x16x32_bf16(kf1, qf[1][1], s[1][ks], 0, 0, 0);
        }
    };

    auto MASK = [&](int kt, f32x4 (*s)[4]) {
        int k0 = kt << 6;
#pragma unroll
        for (int ks = 0; ks < 4; ++ks) {
            int kb_ = k0 + ks * 16 + l4 * 4;
#pragma unroll
            for (int r = 0; r < 4; ++r) {
                int d0 = qg0 - (kb_ + r); int ad0 = d0 < 0 ? -d0 : d0;
                if (ad0 <= WINDOW_) s[0][ks][r] = -1e30f;
                int d1 = qg1 - (kb_ + r); int ad1 = d1 < 0 ? -d1 : d1;
                if (ad1 <= WINDOW_) s[1][ks][r] = -1e30f;
            }
        }
    };

    // pack P (both halves) + rowsum + PV with each V fragment read ONCE
    auto TAIL = [&](auto curc, f32x4 (*s)[4]) {
        constexpr int cur = decltype(curc)::v;
        bf16x8 pa[2][2];
#pragma unroll
        for (int g = 0; g < 2; ++g)
#pragma unroll
            for (int c = 0; c < 2; ++c) {
                pa[g][c][0] = (bf16_t)s[g][2*c][0];   pa[g][c][1] = (bf16_t)s[g][2*c][1];
                pa[g][c][2] = (bf16_t)s[g][2*c][2];   pa[g][c][3] = (bf16_t)s[g][2*c][3];
                pa[g][c][4] = (bf16_t)s[g][2*c+1][0]; pa[g][c][5] = (bf16_t)s[g][2*c+1][1];
                pa[g][c][6] = (bf16_t)s[g][2*c+1][2]; pa[g][c][7] = (bf16_t)s[g][2*c+1][3];
            }
#pragma unroll
        for (int g = 0; g < 2; ++g) {
            osum[g] = __builtin_amdgcn_mfma_f32_16x16x32_bf16(pa[g][0], onesB, osum[g], 0, 0, 0);
            osum[g] = __builtin_amdgcn_mfma_f32_16x16x32_bf16(pa[g][1], onesB, osum[g], 0, 0, 0);
        }
        const char* VL = (const char*)Vsh + cur * 8192;
#pragma unroll
        for (int ns = 0; ns < 4; ++ns) {
            bf16x8 vf0 = *(const bf16x8*)(VL + a0 + ns * 2048);
            bf16x8 vf1 = *(const bf16x8*)(VL + a1 + ns * 2048);
            o[0][ns] = __builtin_amdgcn_mfma_f32_16x16x32_bf16(pa[0][0], vf0, o[0][ns], 0, 0, 0);
            o[1][ns] = __builtin_amdgcn_mfma_f32_16x16x32_bf16(pa[1][0], vf0, o[1][ns], 0, 0, 0);
            o[0][ns] = __builtin_amdgcn_mfma_f32_16x16x32_bf16(pa[0][1], vf1, o[0][ns], 0, 0, 0);
            o[1][ns] = __builtin_amdgcn_mfma_f32_16x16x32_bf16(pa[1][1], vf1, o[1][ns], 0, 0, 0);
        }
    };

    // off = tile offset within stream (1..30); buf parity = off & 1
    auto body = [&](int off, auto curc) {
        if (off < 30) {
            STAGE(NK(tbase + off + 1), IC<(decltype(curc)::v) ^ 1>{});
            asm volatile("s_waitcnt vmcnt(4)" ::: "memory");  // tile `off` landed
        } else {
            asm volatile("s_waitcnt vmcnt(0)" ::: "memory");
        }
        __builtin_amdgcn_s_barrier();
        __builtin_amdgcn_sched_barrier(0);

        int kt = NK(tbase + off);
        int dk = kt - qt2;
        f32x4 s[2][4];
        QK(curc, s, mneg4[0], mneg4[1]);      // C-init = -m: MFMA emits s_raw - m
        if (dk == -2 || dk == -1 || dk == 2 || dk == 3) MASK(kt, s);
#pragma unroll
        for (int g = 0; g < 2; ++g)
#pragma unroll
            for (int ks = 0; ks < 4; ++ks)
#pragma unroll
                for (int r = 0; r < 4; ++r)
                    s[g][ks][r] = fexp2(s[g][ks][r]);
        TAIL(curc, s);
        __builtin_amdgcn_sched_barrier(0);
        __builtin_amdgcn_s_barrier();         // 2-buf safety: writes of off+2 can't pass
    };

    STAGE(NK(tbase), IC<0>{});

    // ---- first tile of this stream: establish frozen m (per half) ----
    {
        STAGE(NK(tbase + 1), IC<1>{});
        asm volatile("s_waitcnt vmcnt(4)" ::: "memory");
        __builtin_amdgcn_s_barrier();
        __builtin_amdgcn_sched_barrier(0);

        int kt = NK(tbase);
        int dk = kt - qt2;
        f32x4 s[2][4];
        QK(IC<0>{}, s, f32x4{0.f,0.f,0.f,0.f}, f32x4{0.f,0.f,0.f,0.f});
        if (dk == -2 || dk == -1 || dk == 2 || dk == 3) MASK(kt, s);
#pragma unroll
        for (int g = 0; g < 2; ++g) {
            float lm = -1e30f;
#pragma unroll
            for (int ks = 0; ks < 4; ++ks) {
                float a = fmaxf(fmaxf(s[g][ks][0], s[g][ks][1]), fmaxf(s[g][ks][2], s[g][ks][3]));
                lm = fmaxf(lm, a);
            }
            lm = fmaxf(lm, __shfl_xor(lm, 16));
            lm = fmaxf(lm, __shfl_xor(lm, 32));
            float m_ = fmaxf(lm, 0.0f);   // guard: rows fully masked in first tile
            mneg4[g] = f32x4{-m_, -m_, -m_, -m_};
#pragma unroll
            for (int ks = 0; ks < 4; ++ks)
#pragma unroll
                for (int r = 0; r < 4; ++r)
                    s[g][ks][r] = fexp2(s[g][ks][r] - m_);
        }
        TAIL(IC<0>{}, s);
        __builtin_amdgcn_sched_barrier(0);
        __builtin_amdgcn_s_barrier();
    }

    for (int j = 0; j < 15; ++j) {
        body(2 * j + 1, IC<1>{});
        body(2 * j + 2, IC<0>{});
    }

    // ---- write partials: o (bf16 [bh][s][64]), osum (f32, D-row indexed) ----
#pragma unroll
    for (int g = 0; g < 2; ++g)
#pragma unroll
        for (int r = 0; r < 4; ++r) {
            int row = wq + g * 16 + l4 * 4 + r;
#pragma unroll
            for (int ns = 0; ns < 4; ++ns)
                po[((long)bh * S_ + row) * 64 + ns * 16 + l15] = (bf16_t)(o[g][ns][r]);
        }
    if (l15 == 0) {
#pragma unroll
        for (int g = 0; g < 2; ++g)
#pragma unroll
            for (int r = 0; r < 4; ++r)
                sums[soff + wq + g * 16 + l4 * 4 + r] = osum[g][r];
    }
    // m is per-q = per-l15 (C-init space!) -> write from lanes 0..15 (l4==0), row = wq+g*16+l15
    if (lane < 16) {
#pragma unroll
        for (int g = 0; g < 2; ++g)
            sums[2 * 24 * S_ + soff + wq + g * 16 + l15] = -mneg4[g][0];
    }
}

// ---------- combine split-K partials: O = (o0 f0 + o1 f1) / (s0 f0 + s1 f1) ----------
__global__ void k_combine(const bf16_t* __restrict__ p0, const bf16_t* __restrict__ p1,
                          const float* __restrict__ sums, bf16_t* __restrict__ ao) {
    int idx = blockIdx.x * 256 + threadIdx.x;   // 24*4096 rows
    int bh = idx >> 12, s = idx & 4095;
    int b = bh / H_, h = bh % H_;
    const float* ms = sums + 2 * 24 * S_;
    float m0 = ms[idx], m1 = ms[24 * S_ + idx];
    float s0 = sums[idx], s1 = sums[24 * S_ + idx];
    float M = fmaxf(m0, m1);
    float f0 = fexp2(m0 - M), f1 = fexp2(m1 - M);
    float inv = 1.0f / (s0 * f0 + s1 * f1);
    float ca = f0 * inv, cb = f1 * inv;
    const bf16x8* qa = (const bf16x8*)(p0 + (long)idx * 64);
    const bf16x8* qb_ = (const bf16x8*)(p1 + (long)idx * 64);
    bf16_t* dst = ao + ((long)b * S_ + s) * E_ + h * 64;
#pragma unroll
    for (int c8 = 0; c8 < 8; ++c8) {
        bf16x8 va = qa[c8], vb = qb_[c8], r;
#pragma unroll
        for (int j = 0; j < 8; ++j)
            r[j] = (bf16_t)((float)va[j] * ca + (float)vb[j] * cb);
        *(bf16x8*)(dst + 8 * c8) = r;
    }
}

extern "C" void kernel_launch(void* const* d_in, const int* in_sizes, int n_in,
                              void* d_out, int out_size, void* d_ws, size_t ws_size,
                              hipStream_t stream) {
    const float* x     = (const float*)d_in[0];
    const float* w_in  = (const float*)d_in[1];
    const float* b_in  = (const float*)d_in[2];
    const float* w_out = (const float*)d_in[3];
    const float* b_out = (const float*)d_in[4];
    float* out = (float*)d_out;

    char* ws = (char*)d_ws;
    bf16_t* xb  = (bf16_t*)(ws + 0);          // 12582912; reused as partial p1 after GEMM0
    bf16_t* wib = (bf16_t*)(ws + 12582912);   // 3538944;  reused as sums/ms after GEMM0
    bf16_t* wob = (bf16_t*)(ws + 16121856);   // 1179648
    bf16_t* qb  = (bf16_t*)(ws + 17301504);   // 12582912; reused as combined attn-out
    bf16_t* kb  = (bf16_t*)(ws + 29884416);   // 12582912
    bf16_t* vtb = (bf16_t*)(ws + 42467328);   // 12582912
    bf16_t* p0  = (bf16_t*)(ws + 55050240);   // 12582912 (proven-free slot)
    bf16_t* p1  = xb;
    float*  sums = (float*)wib;               // [2][24][4096] osum + [2][24][4096] m = 1.57 MB
    bf16_t* ao  = qb;

    k_cvt<<<6144, 256, 0, stream>>>(x, xb, 6291456);
    k_cvt<<<1728, 256, 0, stream>>>(w_in, wib, 1769472);
    k_cvt<<<576, 256, 0, stream>>>(w_out, wob, 589824);

    // QKV projection: M=8192, N=2304, K=768 (v written pre-transposed + pre-permuted)
    k_gemm<0><<<64 * 18, 256, 0, stream>>>(xb, wib, b_in, qb, kb, vtb, nullptr,
                                           8192, 2304, 768, 64);
    // split-K attention partials (2 streams x 31 tiles), then combine
    k_attn_part<<<24 * 32 * 2, 256, 0, stream>>>(qb, kb, vtb, p0, p1, sums);
    k_combine<<<384, 256, 0, stream>>>(p0, p1, sums, ao);
    // out projection: M=8192, N=768, K=768
    k_gemm<1><<<64 * 6, 256, 0, stream>>>(ao, wob, b_out, nullptr, nullptr, nullptr, out,
                                          8192, 768, 768, 64);
}

// Round 15
// 196.117 us; speedup vs baseline: 2.1534x; 2.1534x over previous
//
#include <hip/hip_runtime.h>
#include <hip/hip_bf16.h>
#include <stdint.h>

typedef __bf16 bf16_t;
typedef __bf16 bf16x8 __attribute__((ext_vector_type(8)));
typedef __bf16 bf16x4v __attribute__((ext_vector_type(4)));
typedef float f32x4 __attribute__((ext_vector_type(4)));

#define DEV __device__ __forceinline__

static constexpr int B_ = 2, S_ = 4096, E_ = 768, H_ = 12, D_ = 64;
static constexpr int WINDOW_ = 128;
static constexpr float QSCALE = 0.125f * 1.44269504088896f;  // fold log2(e): softmax via exp2

template<int C> struct IC { static constexpr int v = C; };

// fast exp2: single v_exp_f32 (1-ulp; flushes large-negative to 0)
DEV float fexp2(float x) { return __builtin_amdgcn_exp2f(x); }

// ---------- async 16B global -> LDS ----------
DEV void gload_lds16(const void* g, void* l) {
    __builtin_amdgcn_global_load_lds(
        (const __attribute__((address_space(1))) uint32_t*)g,
        (__attribute__((address_space(3))) uint32_t*)l, 16, 0, 0);
}

// ---------- fp32 -> bf16 convert ----------
__global__ void k_cvt(const float* __restrict__ in, bf16_t* __restrict__ out, int n) {
    int i = (blockIdx.x * blockDim.x + threadIdx.x) * 4;
    if (i < n) {
        float4 v = *(const float4*)(in + i);
        bf16x4v o;
        o[0] = (bf16_t)v.x; o[1] = (bf16_t)v.y; o[2] = (bf16_t)v.z; o[3] = (bf16_t)v.w;
        *(bf16x4v*)(out + i) = o;
    }
}

// ---------- NT GEMM: C[m][n] = sum_k A[m][k] * Bw[n][k] + bias[n] ----------
// EPI 0: q (scaled, exp2-domain) / k into [B,H,S,D]; v into vt [B,H,D,S] with keys
//        pre-permuted within 32-groups to match the PV A-fragment slot order.
// EPI 1: fp32 output [M][N]
template<int EPI>
__global__ void k_gemm(const bf16_t* __restrict__ A, const bf16_t* __restrict__ Bw,
                       const float* __restrict__ bias,
                       bf16_t* __restrict__ qb, bf16_t* __restrict__ kb, bf16_t* __restrict__ vtb,
                       float* __restrict__ outf,
                       int M, int N, int K, int mtiles) {
    __shared__ bf16_t As[128 * 64];
    __shared__ bf16_t Bs[128 * 64];
    int bid = blockIdx.x;
    int tm = bid % mtiles, tn = bid / mtiles;
    int m0 = tm * 128, n0 = tn * 128;
    int t = threadIdx.x;
    int lane = t & 63, wid = t >> 6;
    int l15 = lane & 15, l4 = lane >> 4;
    int wm = (wid & 1) * 64, wn = (wid >> 1) * 64;

    f32x4 acc[4][4];
#pragma unroll
    for (int i = 0; i < 4; ++i)
#pragma unroll
        for (int j = 0; j < 4; ++j) acc[i][j] = f32x4{0.f, 0.f, 0.f, 0.f};

    for (int kt = 0; kt < K; kt += 64) {
        __syncthreads();
#pragma unroll
        for (int c = 0; c < 4; ++c) {
            int idx = t + 256 * c;
            int row = idx >> 3, part = idx & 7;
            int kc = 8 * (part ^ (row & 7));
            gload_lds16(A + (long)(m0 + row) * K + kt + kc, (char*)As + idx * 16);
            gload_lds16(Bw + (long)(n0 + row) * K + kt + kc, (char*)Bs + idx * 16);
        }
        __syncthreads();
#pragma unroll
        for (int kk = 0; kk < 2; ++kk) {
            bf16x8 af[4], bfr[4];
#pragma unroll
            for (int i = 0; i < 4; ++i) {
                int row = wm + i * 16 + l15;
                int off = row * 128 + ((16 * (kk * 4 + l4)) ^ ((row & 7) << 4));
                af[i] = *(const bf16x8*)((const char*)As + off);
                int rowb = wn + i * 16 + l15;
                int offb = rowb * 128 + ((16 * (kk * 4 + l4)) ^ ((rowb & 7) << 4));
                bfr[i] = *(const bf16x8*)((const char*)Bs + offb);
            }
#pragma unroll
            for (int i = 0; i < 4; ++i)
#pragma unroll
                for (int j = 0; j < 4; ++j)
                    acc[i][j] = __builtin_amdgcn_mfma_f32_16x16x32_bf16(af[i], bfr[j], acc[i][j], 0, 0, 0);
        }
    }

#pragma unroll
    for (int i = 0; i < 4; ++i) {
#pragma unroll
        for (int j = 0; j < 4; ++j) {
            int n = n0 + wn + j * 16 + l15;
            float bv = bias[n];
            int mbase = m0 + wm + i * 16 + l4 * 4;
            if (EPI == 0) {
                int sel = n / 768, nn = n % 768;
                int h = nn >> 6, d = nn & 63;
                int b = mbase >> 12, s = mbase & 4095;
                if (sel == 2) {
                    bf16x4v pk;
#pragma unroll
                    for (int r = 0; r < 4; ++r) pk[r] = (bf16_t)(acc[i][j][r] + bv);
                    // permuted position: slot(8a+j)<-key(4a+j), slot(8a+4+j)<-key(16+4a+j)
                    int pos = (s & ~31) | (((s >> 2) & 3) << 3) | (((s >> 4) & 1) << 2);
                    *(bf16x4v*)(vtb + ((long)(b * H_ + h) * D_ + d) * S_ + pos) = pk;
                } else {
                    long o = ((long)(b * H_ + h) * S_ + s) * D_ + d;
#pragma unroll
                    for (int r = 0; r < 4; ++r) {
                        float v = acc[i][j][r] + bv;
                        if (sel == 0) qb[o + (long)r * D_] = (bf16_t)(v * QSCALE);
                        else          kb[o + (long)r * D_] = (bf16_t)v;
                    }
                }
            } else {
#pragma unroll
                for (int r = 0; r < 4; ++r)
                    outf[(long)(mbase + r) * 768 + n] = acc[i][j][r] + bv;
            }
        }
    }
}

// ---------- attention partials: split-K, 2 streams of 31 K-tiles ----------
// 4 waves x 32 q (two 16-row halves sharing every K/V LDS read), KVBLK=64,
// double-buffered K/V (trailing barrier = provably race-free), frozen-m per stream,
// -m folded into QK MFMA C-init, mfma row-sum. Partial o (bf16) + osum/m (f32) to ws.
// launch_bounds(256,4): VGPR cap 128 (NOT 5 -> cap 102 forced spills, R14 lesson);
// actual ~70 VGPR lets HW still co-schedule 5 blocks/CU (5 x 32KB = 160KB LDS).
__global__ __launch_bounds__(256, 4)
void k_attn_part(const bf16_t* __restrict__ q, const bf16_t* __restrict__ k,
                 const bf16_t* __restrict__ vt,
                 bf16_t* __restrict__ p0, bf16_t* __restrict__ p1,
                 float* __restrict__ sums) {
    __shared__ bf16_t Ksh[2][4096];   // [key][d], 128B rows, 3-bit chunk XOR
    __shared__ bf16_t Vsh[2][4096];   // [d][pos], 128B rows, 3-bit chunk XOR
    int raw = blockIdx.x;
    int sw_ = (raw & 7) * 192 + (raw >> 3);   // XCD-aware swizzle (1536 = 8*192)
    int strm = sw_ & 1;
    int id = sw_ >> 1;
    int bh = id >> 5, qt = id & 31;
    int q0 = qt * 128;
    int t = threadIdx.x, lane = t & 63, wid = t >> 6;
    int l15 = lane & 15, l4 = lane >> 4;

    const bf16_t* qp = q + (long)bh * S_ * D_;
    const bf16_t* kp = k + (long)bh * S_ * D_;
    const bf16_t* vp = vt + (long)bh * D_ * S_;
    bf16_t* po = strm ? p1 : p0;
    int soff = strm * (24 * S_) + bh * S_;
    int wq = q0 + wid * 32;              // this wave's 32 q-rows (2 halves of 16)

    // Q fragments per half (B-operand: col=q=l15, contraction d-chunk 8*l4)
    bf16x8 qf[2][2];
#pragma unroll
    for (int g = 0; g < 2; ++g) {
        int row = wq + g * 16 + l15;
        qf[g][0] = *(const bf16x8*)(qp + (long)row * 64 + 8 * l4);
        qf[g][1] = *(const bf16x8*)(qp + (long)row * 64 + 32 + 8 * l4);
    }

    // LDS fragment addressing: 2 VGPR bases + compile-time immediates
    int sw = (l15 & 7) << 4;
    int a0 = l15 * 128 + ((16 * l4) ^ sw);
    int a1 = a0 ^ 64;

    f32x4 o[2][4], osum[2];
    f32x4 mneg4[2];
#pragma unroll
    for (int g = 0; g < 2; ++g) {
        osum[g] = f32x4{0.f, 0.f, 0.f, 0.f};
        mneg4[g] = f32x4{0.f, 0.f, 0.f, 0.f};
#pragma unroll
        for (int ns = 0; ns < 4; ++ns) o[g][ns] = f32x4{0.f, 0.f, 0.f, 0.f};
    }

    bf16x8 onesB;
#pragma unroll
    for (int j = 0; j < 8; ++j) onesB[j] = (bf16_t)1.0f;

    // staging: 256 threads x (2 K-chunks + 2 V-chunks); linear LDS dest, pre-swizzled src
    int i2b = t + 256;
    int rowA = t >> 3, rowB = i2b >> 3;
    int part = t & 7;
    int koffA = rowA * 64 + 8 * (part ^ (rowA & 7));
    int koffB = rowB * 64 + 8 * (part ^ (rowB & 7));
    int voffA = rowA * S_ + 8 * (part ^ (rowA & 7));
    int voffB = rowB * S_ + 8 * (part ^ (rowB & 7));
    int qt2 = 2 * qt;
    int qg0 = wq + l15;       // g=0 q-row of this lane
    int qg1 = qg0 + 16;       // g=1
    int tbase = strm * 31;    // this stream's tile range: tbase..tbase+30

    auto NK = [&](int i) { return i < qt2 ? i : i + 2; };

    auto STAGE = [&](int kts, auto bufc) {
        constexpr int buf = decltype(bufc)::v;
        char* Kd = (char*)Ksh + buf * 8192 + t * 16;
        char* Vd = (char*)Vsh + buf * 8192 + t * 16;
        long ko = (long)kts << 12;
        int vo = kts << 6;
        gload_lds16(kp + ko + koffA, Kd);
        gload_lds16(kp + ko + koffB, Kd + 4096);
        gload_lds16(vp + vo + voffA, Vd);
        gload_lds16(vp + vo + voffB, Vd + 4096);
    };

    // QK for both halves, each K fragment read ONCE
    auto QK = [&](auto curc, f32x4 (*s)[4], f32x4 ci0, f32x4 ci1) {
        constexpr int cur = decltype(curc)::v;
        const char* KL = (const char*)Ksh + cur * 8192;
#pragma unroll
        for (int ks = 0; ks < 4; ++ks) {
            bf16x8 kf0 = *(const bf16x8*)(KL + a0 + ks * 2048);
            bf16x8 kf1 = *(const bf16x8*)(KL + a1 + ks * 2048);
            s[0][ks] = __builtin_amdgcn_mfma_f32_16x16x32_bf16(kf0, qf[0][0], ci0, 0, 0, 0);
            s[1][ks] = __builtin_amdgcn_mfma_f32_16x16x32_bf16(kf0, qf[1][0], ci1, 0, 0, 0);
            s[0][ks] = __builtin_amdgcn_mfma_f32_16x16x32_bf16(kf1, qf[0][1], s[0][ks], 0, 0, 0);
            s[1][ks] = __builtin_amdgcn_mfma_f32_16x16x32_bf16(kf1, qf[1][1], s[1][ks], 0, 0, 0);
        }
    };

    auto MASK = [&](int kt, f32x4 (*s)[4]) {
        int k0 = kt << 6;
#pragma unroll
        for (int ks = 0; ks < 4; ++ks) {
            int kb_ = k0 + ks * 16 + l4 * 4;
#pragma unroll
            for (int r = 0; r < 4; ++r) {
                int d0 = qg0 - (kb_ + r); int ad0 = d0 < 0 ? -d0 : d0;
                if (ad0 <= WINDOW_) s[0][ks][r] = -1e30f;
                int d1 = qg1 - (kb_ + r); int ad1 = d1 < 0 ? -d1 : d1;
                if (ad1 <= WINDOW_) s[1][ks][r] = -1e30f;
            }
        }
    };

    // pack P (both halves) + rowsum + PV with each V fragment read ONCE
    auto TAIL = [&](auto curc, f32x4 (*s)[4]) {
        constexpr int cur = decltype(curc)::v;
        bf16x8 pa[2][2];
#pragma unroll
        for (int g = 0; g < 2; ++g)
#pragma unroll
            for (int c = 0; c < 2; ++c) {
                pa[g][c][0] = (bf16_t)s[g][2*c][0];   pa[g][c][1] = (bf16_t)s[g][2*c][1];
                pa[g][c][2] = (bf16_t)s[g][2*c][2];   pa[g][c][3] = (bf16_t)s[g][2*c][3];
                pa[g][c][4] = (bf16_t)s[g][2*c+1][0]; pa[g][c][5] = (bf16_t)s[g][2*c+1][1];
                pa[g][c][6] = (bf16_t)s[g][2*c+1][2]; pa[g][c][7] = (bf16_t)s[g][2*c+1][3];
            }
#pragma unroll
        for (int g = 0; g < 2; ++g) {
            osum[g] = __builtin_amdgcn_mfma_f32_16x16x32_bf16(pa[g][0], onesB, osum[g], 0, 0, 0);
            osum[g] = __builtin_amdgcn_mfma_f32_16x16x32_bf16(pa[g][1], onesB, osum[g], 0, 0, 0);
        }
        const char* VL = (const char*)Vsh + cur * 8192;
#pragma unroll
        for (int ns = 0; ns < 4; ++ns) {
            bf16x8 vf0 = *(const bf16x8*)(VL + a0 + ns * 2048);
            bf16x8 vf1 = *(const bf16x8*)(VL + a1 + ns * 2048);
            o[0][ns] = __builtin_amdgcn_mfma_f32_16x16x32_bf16(pa[0][0], vf0, o[0][ns], 0, 0, 0);
            o[1][ns] = __builtin_amdgcn_mfma_f32_16x16x32_bf16(pa[1][0], vf0, o[1][ns], 0, 0, 0);
            o[0][ns] = __builtin_amdgcn_mfma_f32_16x16x32_bf16(pa[0][1], vf1, o[0][ns], 0, 0, 0);
            o[1][ns] = __builtin_amdgcn_mfma_f32_16x16x32_bf16(pa[1][1], vf1, o[1][ns], 0, 0, 0);
        }
    };

    // off = tile offset within stream (1..30); buf parity = off & 1
    auto body = [&](int off, auto curc) {
        if (off < 30) {
            STAGE(NK(tbase + off + 1), IC<(decltype(curc)::v) ^ 1>{});
            asm volatile("s_waitcnt vmcnt(4)" ::: "memory");  // tile `off` landed
        } else {
            asm volatile("s_waitcnt vmcnt(0)" ::: "memory");
        }
        __builtin_amdgcn_s_barrier();
        __builtin_amdgcn_sched_barrier(0);

        int kt = NK(tbase + off);
        int dk = kt - qt2;
        f32x4 s[2][4];
        QK(curc, s, mneg4[0], mneg4[1]);      // C-init = -m: MFMA emits s_raw - m
        if (dk == -2 || dk == -1 || dk == 2 || dk == 3) MASK(kt, s);
#pragma unroll
        for (int g = 0; g < 2; ++g)
#pragma unroll
            for (int ks = 0; ks < 4; ++ks)
#pragma unroll
                for (int r = 0; r < 4; ++r)
                    s[g][ks][r] = fexp2(s[g][ks][r]);
        TAIL(curc, s);
        __builtin_amdgcn_sched_barrier(0);
        __builtin_amdgcn_s_barrier();         // 2-buf safety: writes of off+2 can't pass
    };

    STAGE(NK(tbase), IC<0>{});

    // ---- first tile of this stream: establish frozen m (per half) ----
    {
        STAGE(NK(tbase + 1), IC<1>{});
        asm volatile("s_waitcnt vmcnt(4)" ::: "memory");
        __builtin_amdgcn_s_barrier();
        __builtin_amdgcn_sched_barrier(0);

        int kt = NK(tbase);
        int dk = kt - qt2;
        f32x4 s[2][4];
        QK(IC<0>{}, s, f32x4{0.f,0.f,0.f,0.f}, f32x4{0.f,0.f,0.f,0.f});
        if (dk == -2 || dk == -1 || dk == 2 || dk == 3) MASK(kt, s);
#pragma unroll
        for (int g = 0; g < 2; ++g) {
            float lm = -1e30f;
#pragma unroll
            for (int ks = 0; ks < 4; ++ks) {
                float a = fmaxf(fmaxf(s[g][ks][0], s[g][ks][1]), fmaxf(s[g][ks][2], s[g][ks][3]));
                lm = fmaxf(lm, a);
            }
            lm = fmaxf(lm, __shfl_xor(lm, 16));
            lm = fmaxf(lm, __shfl_xor(lm, 32));
            float m_ = fmaxf(lm, 0.0f);   // guard: rows fully masked in first tile
            mneg4[g] = f32x4{-m_, -m_, -m_, -m_};
#pragma unroll
            for (int ks = 0; ks < 4; ++ks)
#pragma unroll
                for (int r = 0; r < 4; ++r)
                    s[g][ks][r] = fexp2(s[g][ks][r] - m_);
        }
        TAIL(IC<0>{}, s);
        __builtin_amdgcn_sched_barrier(0);
        __builtin_amdgcn_s_barrier();
    }

    for (int j = 0; j < 15; ++j) {
        body(2 * j + 1, IC<1>{});
        body(2 * j + 2, IC<0>{});
    }

    // ---- write partials: o (bf16 [bh][s][64]), osum (f32, D-row indexed) ----
#pragma unroll
    for (int g = 0; g < 2; ++g)
#pragma unroll
        for (int r = 0; r < 4; ++r) {
            int row = wq + g * 16 + l4 * 4 + r;
#pragma unroll
            for (int ns = 0; ns < 4; ++ns)
                po[((long)bh * S_ + row) * 64 + ns * 16 + l15] = (bf16_t)(o[g][ns][r]);
        }
    if (l15 == 0) {
#pragma unroll
        for (int g = 0; g < 2; ++g)
#pragma unroll
            for (int r = 0; r < 4; ++r)
                sums[soff + wq + g * 16 + l4 * 4 + r] = osum[g][r];
    }
    // m is per-q = per-l15 (C-init space!) -> write from lanes 0..15 (l4==0), row = wq+g*16+l15
    if (lane < 16) {
#pragma unroll
        for (int g = 0; g < 2; ++g)
            sums[2 * 24 * S_ + soff + wq + g * 16 + l15] = -mneg4[g][0];
    }
}

// ---------- combine split-K partials: O = (o0 f0 + o1 f1) / (s0 f0 + s1 f1) ----------
__global__ void k_combine(const bf16_t* __restrict__ p0, const bf16_t* __restrict__ p1,
                          const float* __restrict__ sums, bf16_t* __restrict__ ao) {
    int idx = blockIdx.x * 256 + threadIdx.x;   // 24*4096 rows
    int bh = idx >> 12, s = idx & 4095;
    int b = bh / H_, h = bh % H_;
    const float* ms = sums + 2 * 24 * S_;
    float m0 = ms[idx], m1 = ms[24 * S_ + idx];
    float s0 = sums[idx], s1 = sums[24 * S_ + idx];
    float M = fmaxf(m0, m1);
    float f0 = fexp2(m0 - M), f1 = fexp2(m1 - M);
    float inv = 1.0f / (s0 * f0 + s1 * f1);
    float ca = f0 * inv, cb = f1 * inv;
    const bf16x8* qa = (const bf16x8*)(p0 + (long)idx * 64);
    const bf16x8* qb_ = (const bf16x8*)(p1 + (long)idx * 64);
    bf16_t* dst = ao + ((long)b * S_ + s) * E_ + h * 64;
#pragma unroll
    for (int c8 = 0; c8 < 8; ++c8) {
        bf16x8 va = qa[c8], vb = qb_[c8], r;
#pragma unroll
        for (int j = 0; j < 8; ++j)
            r[j] = (bf16_t)((float)va[j] * ca + (float)vb[j] * cb);
        *(bf16x8*)(dst + 8 * c8) = r;
    }
}

extern "C" void kernel_launch(void* const* d_in, const int* in_sizes, int n_in,
                              void* d_out, int out_size, void* d_ws, size_t ws_size,
                              hipStream_t stream) {
    const float* x     = (const float*)d_in[0];
    const float* w_in  = (const float*)d_in[1];
    const float* b_in  = (const float*)d_in[2];
    const float* w_out = (const float*)d_in[3];
    const float* b_out = (const float*)d_in[4];
    float* out = (float*)d_out;

    char* ws = (char*)d_ws;
    bf16_t* xb  = (bf16_t*)(ws + 0);          // 12582912; reused as partial p1 after GEMM0
    bf16_t* wib = (bf16_t*)(ws + 12582912);   // 3538944;  reused as sums/ms after GEMM0
    bf16_t* wob = (bf16_t*)(ws + 16121856);   // 1179648
    bf16_t* qb  = (bf16_t*)(ws + 17301504);   // 12582912; reused as combined attn-out
    bf16_t* kb  = (bf16_t*)(ws + 29884416);   // 12582912
    bf16_t* vtb = (bf16_t*)(ws + 42467328);   // 12582912
    bf16_t* p0  = (bf16_t*)(ws + 55050240);   // 12582912 (proven-free slot)
    bf16_t* p1  = xb;
    float*  sums = (float*)wib;               // [2][24][4096] osum + [2][24][4096] m = 1.57 MB
    bf16_t* ao  = qb;

    k_cvt<<<6144, 256, 0, stream>>>(x, xb, 6291456);
    k_cvt<<<1728, 256, 0, stream>>>(w_in, wib, 1769472);
    k_cvt<<<576, 256, 0, stream>>>(w_out, wob, 589824);

    // QKV projection: M=8192, N=2304, K=768 (v written pre-transposed + pre-permuted)
    k_gemm<0><<<64 * 18, 256, 0, stream>>>(xb, wib, b_in, qb, kb, vtb, nullptr,
                                           8192, 2304, 768, 64);
    // split-K attention partials (2 streams x 31 tiles), then combine
    k_attn_part<<<24 * 32 * 2, 256, 0, stream>>>(qb, kb, vtb, p0, p1, sums);
    k_combine<<<384, 256, 0, stream>>>(p0, p1, sums, ao);
    // out projection: M=8192, N=768, K=768
    k_gemm<1><<<64 * 6, 256, 0, stream>>>(ao, wob, b_out, nullptr, nullptr, nullptr, out,
                                          8192, 768, 768, 64);
}

// Round 16
// 184.358 us; speedup vs baseline: 2.2907x; 1.0638x over previous
//
#include <hip/hip_runtime.h>
#include <hip/hip_bf16.h>
#include <stdint.h>

typedef __bf16 bf16_t;
typedef __bf16 bf16x8 __attribute__((ext_vector_type(8)));
typedef __bf16 bf16x4v __attribute__((ext_vector_type(4)));
typedef float f32x4 __attribute__((ext_vector_type(4)));

#define DEV __device__ __forceinline__

static constexpr int B_ = 2, S_ = 4096, E_ = 768, H_ = 12, D_ = 64;
static constexpr int WINDOW_ = 128;
static constexpr float QSCALE = 0.125f * 1.44269504088896f;  // fold log2(e): softmax via exp2

template<int C> struct IC { static constexpr int v = C; };

// fast exp2: single v_exp_f32 (1-ulp; flushes large-negative to 0)
DEV float fexp2(float x) { return __builtin_amdgcn_exp2f(x); }

// ---------- async 16B global -> LDS ----------
DEV void gload_lds16(const void* g, void* l) {
    __builtin_amdgcn_global_load_lds(
        (const __attribute__((address_space(1))) uint32_t*)g,
        (__attribute__((address_space(3))) uint32_t*)l, 16, 0, 0);
}

// ---------- fp32 -> bf16 convert ----------
__global__ void k_cvt(const float* __restrict__ in, bf16_t* __restrict__ out, int n) {
    int i = (blockIdx.x * blockDim.x + threadIdx.x) * 4;
    if (i < n) {
        float4 v = *(const float4*)(in + i);
        bf16x4v o;
        o[0] = (bf16_t)v.x; o[1] = (bf16_t)v.y; o[2] = (bf16_t)v.z; o[3] = (bf16_t)v.w;
        *(bf16x4v*)(out + i) = o;
    }
}

// ---------- NT GEMM: C[m][n] = sum_k A[m][k] * Bw[n][k] + bias[n] ----------
// EPI 0: q (scaled, exp2-domain) / k into [B,H,S,D]; v into vt [B,H,D,S] with keys
//        pre-permuted within 32-groups to match the PV A-fragment slot order.
// EPI 1: fp32 output [M][N]
template<int EPI>
__global__ void k_gemm(const bf16_t* __restrict__ A, const bf16_t* __restrict__ Bw,
                       const float* __restrict__ bias,
                       bf16_t* __restrict__ qb, bf16_t* __restrict__ kb, bf16_t* __restrict__ vtb,
                       float* __restrict__ outf,
                       int M, int N, int K, int mtiles) {
    __shared__ bf16_t As[128 * 64];
    __shared__ bf16_t Bs[128 * 64];
    int bid = blockIdx.x;
    int tm = bid % mtiles, tn = bid / mtiles;
    int m0 = tm * 128, n0 = tn * 128;
    int t = threadIdx.x;
    int lane = t & 63, wid = t >> 6;
    int l15 = lane & 15, l4 = lane >> 4;
    int wm = (wid & 1) * 64, wn = (wid >> 1) * 64;

    f32x4 acc[4][4];
#pragma unroll
    for (int i = 0; i < 4; ++i)
#pragma unroll
        for (int j = 0; j < 4; ++j) acc[i][j] = f32x4{0.f, 0.f, 0.f, 0.f};

    for (int kt = 0; kt < K; kt += 64) {
        __syncthreads();
#pragma unroll
        for (int c = 0; c < 4; ++c) {
            int idx = t + 256 * c;
            int row = idx >> 3, part = idx & 7;
            int kc = 8 * (part ^ (row & 7));
            gload_lds16(A + (long)(m0 + row) * K + kt + kc, (char*)As + idx * 16);
            gload_lds16(Bw + (long)(n0 + row) * K + kt + kc, (char*)Bs + idx * 16);
        }
        __syncthreads();
#pragma unroll
        for (int kk = 0; kk < 2; ++kk) {
            bf16x8 af[4], bfr[4];
#pragma unroll
            for (int i = 0; i < 4; ++i) {
                int row = wm + i * 16 + l15;
                int off = row * 128 + ((16 * (kk * 4 + l4)) ^ ((row & 7) << 4));
                af[i] = *(const bf16x8*)((const char*)As + off);
                int rowb = wn + i * 16 + l15;
                int offb = rowb * 128 + ((16 * (kk * 4 + l4)) ^ ((rowb & 7) << 4));
                bfr[i] = *(const bf16x8*)((const char*)Bs + offb);
            }
#pragma unroll
            for (int i = 0; i < 4; ++i)
#pragma unroll
                for (int j = 0; j < 4; ++j)
                    acc[i][j] = __builtin_amdgcn_mfma_f32_16x16x32_bf16(af[i], bfr[j], acc[i][j], 0, 0, 0);
        }
    }

#pragma unroll
    for (int i = 0; i < 4; ++i) {
#pragma unroll
        for (int j = 0; j < 4; ++j) {
            int n = n0 + wn + j * 16 + l15;
            float bv = bias[n];
            int mbase = m0 + wm + i * 16 + l4 * 4;
            if (EPI == 0) {
                int sel = n / 768, nn = n % 768;
                int h = nn >> 6, d = nn & 63;
                int b = mbase >> 12, s = mbase & 4095;
                if (sel == 2) {
                    bf16x4v pk;
#pragma unroll
                    for (int r = 0; r < 4; ++r) pk[r] = (bf16_t)(acc[i][j][r] + bv);
                    // permuted position: slot(8a+j)<-key(4a+j), slot(8a+4+j)<-key(16+4a+j)
                    int pos = (s & ~31) | (((s >> 2) & 3) << 3) | (((s >> 4) & 1) << 2);
                    *(bf16x4v*)(vtb + ((long)(b * H_ + h) * D_ + d) * S_ + pos) = pk;
                } else {
                    long o = ((long)(b * H_ + h) * S_ + s) * D_ + d;
#pragma unroll
                    for (int r = 0; r < 4; ++r) {
                        float v = acc[i][j][r] + bv;
                        if (sel == 0) qb[o + (long)r * D_] = (bf16_t)(v * QSCALE);
                        else          kb[o + (long)r * D_] = (bf16_t)v;
                    }
                }
            } else {
#pragma unroll
                for (int r = 0; r < 4; ++r)
                    outf[(long)(mbase + r) * 768 + n] = acc[i][j][r] + bv;
            }
        }
    }
}

// ---------- attention: swapped QK^T, frozen-m softmax, in-register P ----------
// 4 waves x 32 q (two 16-row halves sharing every K/V LDS read), KVBLK=64,
// triple-buffered K/V with TWO-DEEP prefetch: body(t) = vmcnt(t's loads, issued
// two bodies ago) -> barrier -> STAGE(t+2) -> compute. One barrier per tile.
__global__ __launch_bounds__(256, 3)
void k_attn(const bf16_t* __restrict__ q, const bf16_t* __restrict__ k,
            const bf16_t* __restrict__ vt, bf16_t* __restrict__ ao) {
    __shared__ bf16_t Ksh[3][4096];   // [key][d], 128B rows, 3-bit chunk XOR
    __shared__ bf16_t Vsh[3][4096];   // [d][pos], 128B rows, 3-bit chunk XOR
    int bid = blockIdx.x;
    bid = (bid & 7) * 96 + (bid >> 3);    // XCD-aware swizzle (768 = 8*96)
    int bh = bid >> 5, qt = bid & 31;
    int q0 = qt * 128;
    int b = bh / H_, h = bh % H_;
    int t = threadIdx.x, lane = t & 63, wid = t >> 6;
    int l15 = lane & 15, l4 = lane >> 4;

    const bf16_t* qp = q + (long)bh * S_ * D_;
    const bf16_t* kp = k + (long)bh * S_ * D_;
    const bf16_t* vp = vt + (long)bh * D_ * S_;
    int wq = q0 + wid * 32;              // this wave's 32 q-rows (2 halves of 16)

    // Q fragments per half (B-operand: col=q=l15, contraction d-chunk 8*l4)
    bf16x8 qf[2][2];
#pragma unroll
    for (int g = 0; g < 2; ++g) {
        int row = wq + g * 16 + l15;
        qf[g][0] = *(const bf16x8*)(qp + (long)row * 64 + 8 * l4);
        qf[g][1] = *(const bf16x8*)(qp + (long)row * 64 + 32 + 8 * l4);
    }

    // LDS fragment addressing: 2 VGPR bases + compile-time immediates
    int sw = (l15 & 7) << 4;
    int a0 = l15 * 128 + ((16 * l4) ^ sw);
    int a1 = a0 ^ 64;

    f32x4 o[2][4], osum[2];
    f32x4 mneg4[2];
#pragma unroll
    for (int g = 0; g < 2; ++g) {
        osum[g] = f32x4{0.f, 0.f, 0.f, 0.f};
        mneg4[g] = f32x4{0.f, 0.f, 0.f, 0.f};
#pragma unroll
        for (int ns = 0; ns < 4; ++ns) o[g][ns] = f32x4{0.f, 0.f, 0.f, 0.f};
    }

    bf16x8 onesB;
#pragma unroll
    for (int j = 0; j < 8; ++j) onesB[j] = (bf16_t)1.0f;

    // staging: 256 threads x (2 K-chunks + 2 V-chunks); linear LDS dest, pre-swizzled src
    int i2b = t + 256;
    int rowA = t >> 3, rowB = i2b >> 3;
    int part = t & 7;
    int koffA = rowA * 64 + 8 * (part ^ (rowA & 7));
    int koffB = rowB * 64 + 8 * (part ^ (rowB & 7));
    int voffA = rowA * S_ + 8 * (part ^ (rowA & 7));
    int voffB = rowB * S_ + 8 * (part ^ (rowB & 7));
    int qt2 = 2 * qt;
    int qg0 = wq + l15;       // g=0 q-row of this lane
    int qg1 = qg0 + 16;       // g=1

    auto NK = [&](int i) { return i < qt2 ? i : i + 2; };

    auto STAGE = [&](int kts, auto bufc) {
        constexpr int buf = decltype(bufc)::v;
        char* Kd = (char*)Ksh + buf * 8192 + t * 16;
        char* Vd = (char*)Vsh + buf * 8192 + t * 16;
        long ko = (long)kts << 12;
        int vo = kts << 6;
        gload_lds16(kp + ko + koffA, Kd);
        gload_lds16(kp + ko + koffB, Kd + 4096);
        gload_lds16(vp + vo + voffA, Vd);
        gload_lds16(vp + vo + voffB, Vd + 4096);
    };

    // QK for both halves, each K fragment read ONCE
    auto QK = [&](auto curc, f32x4 (*s)[4], f32x4 ci0, f32x4 ci1) {
        constexpr int cur = decltype(curc)::v;
        const char* KL = (const char*)Ksh + cur * 8192;
#pragma unroll
        for (int ks = 0; ks < 4; ++ks) {
            bf16x8 kf0 = *(const bf16x8*)(KL + a0 + ks * 2048);
            bf16x8 kf1 = *(const bf16x8*)(KL + a1 + ks * 2048);
            s[0][ks] = __builtin_amdgcn_mfma_f32_16x16x32_bf16(kf0, qf[0][0], ci0, 0, 0, 0);
            s[1][ks] = __builtin_amdgcn_mfma_f32_16x16x32_bf16(kf0, qf[1][0], ci1, 0, 0, 0);
            s[0][ks] = __builtin_amdgcn_mfma_f32_16x16x32_bf16(kf1, qf[0][1], s[0][ks], 0, 0, 0);
            s[1][ks] = __builtin_amdgcn_mfma_f32_16x16x32_bf16(kf1, qf[1][1], s[1][ks], 0, 0, 0);
        }
    };

    auto MASK = [&](int kt, f32x4 (*s)[4]) {
        int k0 = kt << 6;
#pragma unroll
        for (int ks = 0; ks < 4; ++ks) {
            int kb_ = k0 + ks * 16 + l4 * 4;
#pragma unroll
            for (int r = 0; r < 4; ++r) {
                int d0 = qg0 - (kb_ + r); int ad0 = d0 < 0 ? -d0 : d0;
                if (ad0 <= WINDOW_) s[0][ks][r] = -1e30f;
                int d1 = qg1 - (kb_ + r); int ad1 = d1 < 0 ? -d1 : d1;
                if (ad1 <= WINDOW_) s[1][ks][r] = -1e30f;
            }
        }
    };

    // pack P (both halves) + rowsum + PV with each V fragment read ONCE
    auto TAIL = [&](auto curc, f32x4 (*s)[4]) {
        constexpr int cur = decltype(curc)::v;
        bf16x8 pa[2][2];
#pragma unroll
        for (int g = 0; g < 2; ++g)
#pragma unroll
            for (int c = 0; c < 2; ++c) {
                pa[g][c][0] = (bf16_t)s[g][2*c][0];   pa[g][c][1] = (bf16_t)s[g][2*c][1];
                pa[g][c][2] = (bf16_t)s[g][2*c][2];   pa[g][c][3] = (bf16_t)s[g][2*c][3];
                pa[g][c][4] = (bf16_t)s[g][2*c+1][0]; pa[g][c][5] = (bf16_t)s[g][2*c+1][1];
                pa[g][c][6] = (bf16_t)s[g][2*c+1][2]; pa[g][c][7] = (bf16_t)s[g][2*c+1][3];
            }
#pragma unroll
        for (int g = 0; g < 2; ++g) {
            osum[g] = __builtin_amdgcn_mfma_f32_16x16x32_bf16(pa[g][0], onesB, osum[g], 0, 0, 0);
            osum[g] = __builtin_amdgcn_mfma_f32_16x16x32_bf16(pa[g][1], onesB, osum[g], 0, 0, 0);
        }
        const char* VL = (const char*)Vsh + cur * 8192;
#pragma unroll
        for (int ns = 0; ns < 4; ++ns) {
            bf16x8 vf0 = *(const bf16x8*)(VL + a0 + ns * 2048);
            bf16x8 vf1 = *(const bf16x8*)(VL + a1 + ns * 2048);
            o[0][ns] = __builtin_amdgcn_mfma_f32_16x16x32_bf16(pa[0][0], vf0, o[0][ns], 0, 0, 0);
            o[1][ns] = __builtin_amdgcn_mfma_f32_16x16x32_bf16(pa[1][0], vf0, o[1][ns], 0, 0, 0);
            o[0][ns] = __builtin_amdgcn_mfma_f32_16x16x32_bf16(pa[0][1], vf1, o[0][ns], 0, 0, 0);
            o[1][ns] = __builtin_amdgcn_mfma_f32_16x16x32_bf16(pa[1][1], vf1, o[1][ns], 0, 0, 0);
        }
    };

    // body(t): vmcnt(t's loads, issued 2 bodies ago) -> barrier -> STAGE(t+2) -> compute(t)
    auto body = [&](int idx, auto curc) {
        if (idx < 61) {
            asm volatile("s_waitcnt vmcnt(4)" ::: "memory");
        } else {
            asm volatile("s_waitcnt vmcnt(0)" ::: "memory");
        }
        __builtin_amdgcn_s_barrier();
        if (idx + 2 < 62)
            STAGE(NK(idx + 2), IC<(decltype(curc)::v + 2) % 3>{});
        __builtin_amdgcn_sched_barrier(0);

        int kt = NK(idx);
        int dk = kt - qt2;
        f32x4 s[2][4];
        QK(curc, s, mneg4[0], mneg4[1]);      // C-init = -m: MFMA emits s_raw - m
        if (dk == -2 || dk == -1 || dk == 2 || dk == 3) MASK(kt, s);
#pragma unroll
        for (int g = 0; g < 2; ++g)
#pragma unroll
            for (int ks = 0; ks < 4; ++ks)
#pragma unroll
                for (int r = 0; r < 4; ++r)
                    s[g][ks][r] = fexp2(s[g][ks][r]);
        TAIL(curc, s);
    };

    // prologue: two tiles in flight before first compute
    STAGE(NK(0), IC<0>{});
    STAGE(NK(1), IC<1>{});

    // ---- first tile: establish frozen m (per half) ----
    {
        asm volatile("s_waitcnt vmcnt(4)" ::: "memory");   // own tile-0 loads landed
        __builtin_amdgcn_s_barrier();                      // all waves' tile-0 loads landed
        STAGE(NK(2), IC<2>{});
        __builtin_amdgcn_sched_barrier(0);

        int kt = NK(0);
        int dk = kt - qt2;
        f32x4 s[2][4];
        QK(IC<0>{}, s, f32x4{0.f,0.f,0.f,0.f}, f32x4{0.f,0.f,0.f,0.f});
        if (dk == -2 || dk == -1 || dk == 2 || dk == 3) MASK(kt, s);
#pragma unroll
        for (int g = 0; g < 2; ++g) {
            float lm = -1e30f;
#pragma unroll
            for (int ks = 0; ks < 4; ++ks) {
                float a = fmaxf(fmaxf(s[g][ks][0], s[g][ks][1]), fmaxf(s[g][ks][2], s[g][ks][3]));
                lm = fmaxf(lm, a);
            }
            lm = fmaxf(lm, __shfl_xor(lm, 16));
            lm = fmaxf(lm, __shfl_xor(lm, 32));
            float m_ = fmaxf(lm, 0.0f);   // guard: rows fully masked in first tile
            mneg4[g] = f32x4{-m_, -m_, -m_, -m_};
#pragma unroll
            for (int ks = 0; ks < 4; ++ks)
#pragma unroll
                for (int r = 0; r < 4; ++r)
                    s[g][ks][r] = fexp2(s[g][ks][r] - m_);
        }
        TAIL(IC<0>{}, s);
    }

    for (int i3 = 0; i3 < 20; ++i3) {
        body(3 * i3 + 1, IC<1>{});
        body(3 * i3 + 2, IC<2>{});
        body(3 * i3 + 3, IC<0>{});
    }
    body(61, IC<1>{});

    // finalize + write [B,S,E] bf16 (osum row-aligned with o)
#pragma unroll
    for (int g = 0; g < 2; ++g)
#pragma unroll
        for (int r = 0; r < 4; ++r) {
            float ir = 1.0f / osum[g][r];
            int srow2 = wq + g * 16 + l4 * 4 + r;
#pragma unroll
            for (int ns = 0; ns < 4; ++ns) {
                int e = h * 64 + ns * 16 + l15;
                ao[((long)b * S_ + srow2) * E_ + e] = (bf16_t)(o[g][ns][r] * ir);
            }
        }
}

extern "C" void kernel_launch(void* const* d_in, const int* in_sizes, int n_in,
                              void* d_out, int out_size, void* d_ws, size_t ws_size,
                              hipStream_t stream) {
    const float* x     = (const float*)d_in[0];
    const float* w_in  = (const float*)d_in[1];
    const float* b_in  = (const float*)d_in[2];
    const float* w_out = (const float*)d_in[3];
    const float* b_out = (const float*)d_in[4];
    float* out = (float*)d_out;

    char* ws = (char*)d_ws;
    bf16_t* xb  = (bf16_t*)(ws + 0);          // 12582912 (reused as attn-out)
    bf16_t* wib = (bf16_t*)(ws + 12582912);   // 3538944
    bf16_t* wob = (bf16_t*)(ws + 16121856);   // 1179648
    bf16_t* qb  = (bf16_t*)(ws + 17301504);   // 12582912
    bf16_t* kb  = (bf16_t*)(ws + 29884416);   // 12582912
    bf16_t* vtb = (bf16_t*)(ws + 42467328);   // 12582912
    bf16_t* ao  = xb;

    k_cvt<<<6144, 256, 0, stream>>>(x, xb, 6291456);
    k_cvt<<<1728, 256, 0, stream>>>(w_in, wib, 1769472);
    k_cvt<<<576, 256, 0, stream>>>(w_out, wob, 589824);

    // QKV projection: M=8192, N=2304, K=768 (v written pre-transposed + pre-permuted)
    k_gemm<0><<<64 * 18, 256, 0, stream>>>(xb, wib, b_in, qb, kb, vtb, nullptr,
                                           8192, 2304, 768, 64);
    k_attn<<<24 * 32, 256, 0, stream>>>(qb, kb, vtb, ao);
    // out projection: M=8192, N=768, K=768
    k_gemm<1><<<64 * 6, 256, 0, stream>>>(ao, wob, b_out, nullptr, nullptr, nullptr, out,
                                          8192, 768, 768, 64);
}

// Round 17
// 183.798 us; speedup vs baseline: 2.2977x; 1.0030x over previous
//
#include <hip/hip_runtime.h>
#include <hip/hip_bf16.h>
#include <stdint.h>

typedef __bf16 bf16_t;
typedef __bf16 bf16x8 __attribute__((ext_vector_type(8)));
typedef __bf16 bf16x4v __attribute__((ext_vector_type(4)));
typedef float f32x4 __attribute__((ext_vector_type(4)));

#define DEV __device__ __forceinline__

static constexpr int B_ = 2, S_ = 4096, E_ = 768, H_ = 12, D_ = 64;
static constexpr int WINDOW_ = 128;
static constexpr float QSCALE = 0.125f * 1.44269504088896f;  // fold log2(e): softmax via exp2

template<int C> struct IC { static constexpr int v = C; };

// fast exp2: single v_exp_f32 (1-ulp; flushes large-negative to 0)
DEV float fexp2(float x) { return __builtin_amdgcn_exp2f(x); }

// ---------- async 16B global -> LDS ----------
DEV void gload_lds16(const void* g, void* l) {
    __builtin_amdgcn_global_load_lds(
        (const __attribute__((address_space(1))) uint32_t*)g,
        (__attribute__((address_space(3))) uint32_t*)l, 16, 0, 0);
}

// ---------- fp32 -> bf16 convert ----------
__global__ void k_cvt(const float* __restrict__ in, bf16_t* __restrict__ out, int n) {
    int i = (blockIdx.x * blockDim.x + threadIdx.x) * 4;
    if (i < n) {
        float4 v = *(const float4*)(in + i);
        bf16x4v o;
        o[0] = (bf16_t)v.x; o[1] = (bf16_t)v.y; o[2] = (bf16_t)v.z; o[3] = (bf16_t)v.w;
        *(bf16x4v*)(out + i) = o;
    }
}

// ---------- NT GEMM: C[m][n] = sum_k A[m][k] * Bw[n][k] + bias[n] ----------
// EPI 0: q (scaled, exp2-domain) / k into [B,H,S,D]; v into vt [B,H,D,S] with keys
//        pre-permuted within 32-groups to match the PV A-fragment slot order.
// EPI 1: fp32 output [M][N]
template<int EPI>
__global__ void k_gemm(const bf16_t* __restrict__ A, const bf16_t* __restrict__ Bw,
                       const float* __restrict__ bias,
                       bf16_t* __restrict__ qb, bf16_t* __restrict__ kb, bf16_t* __restrict__ vtb,
                       float* __restrict__ outf,
                       int M, int N, int K, int mtiles) {
    __shared__ bf16_t As[128 * 64];
    __shared__ bf16_t Bs[128 * 64];
    int bid = blockIdx.x;
    int tm = bid % mtiles, tn = bid / mtiles;
    int m0 = tm * 128, n0 = tn * 128;
    int t = threadIdx.x;
    int lane = t & 63, wid = t >> 6;
    int l15 = lane & 15, l4 = lane >> 4;
    int wm = (wid & 1) * 64, wn = (wid >> 1) * 64;

    f32x4 acc[4][4];
#pragma unroll
    for (int i = 0; i < 4; ++i)
#pragma unroll
        for (int j = 0; j < 4; ++j) acc[i][j] = f32x4{0.f, 0.f, 0.f, 0.f};

    for (int kt = 0; kt < K; kt += 64) {
        __syncthreads();
#pragma unroll
        for (int c = 0; c < 4; ++c) {
            int idx = t + 256 * c;
            int row = idx >> 3, part = idx & 7;
            int kc = 8 * (part ^ (row & 7));
            gload_lds16(A + (long)(m0 + row) * K + kt + kc, (char*)As + idx * 16);
            gload_lds16(Bw + (long)(n0 + row) * K + kt + kc, (char*)Bs + idx * 16);
        }
        __syncthreads();
#pragma unroll
        for (int kk = 0; kk < 2; ++kk) {
            bf16x8 af[4], bfr[4];
#pragma unroll
            for (int i = 0; i < 4; ++i) {
                int row = wm + i * 16 + l15;
                int off = row * 128 + ((16 * (kk * 4 + l4)) ^ ((row & 7) << 4));
                af[i] = *(const bf16x8*)((const char*)As + off);
                int rowb = wn + i * 16 + l15;
                int offb = rowb * 128 + ((16 * (kk * 4 + l4)) ^ ((rowb & 7) << 4));
                bfr[i] = *(const bf16x8*)((const char*)Bs + offb);
            }
#pragma unroll
            for (int i = 0; i < 4; ++i)
#pragma unroll
                for (int j = 0; j < 4; ++j)
                    acc[i][j] = __builtin_amdgcn_mfma_f32_16x16x32_bf16(af[i], bfr[j], acc[i][j], 0, 0, 0);
        }
    }

#pragma unroll
    for (int i = 0; i < 4; ++i) {
#pragma unroll
        for (int j = 0; j < 4; ++j) {
            int n = n0 + wn + j * 16 + l15;
            float bv = bias[n];
            int mbase = m0 + wm + i * 16 + l4 * 4;
            if (EPI == 0) {
                int sel = n / 768, nn = n % 768;
                int h = nn >> 6, d = nn & 63;
                int b = mbase >> 12, s = mbase & 4095;
                if (sel == 2) {
                    bf16x4v pk;
#pragma unroll
                    for (int r = 0; r < 4; ++r) pk[r] = (bf16_t)(acc[i][j][r] + bv);
                    // permuted position: slot(8a+j)<-key(4a+j), slot(8a+4+j)<-key(16+4a+j)
                    int pos = (s & ~31) | (((s >> 2) & 3) << 3) | (((s >> 4) & 1) << 2);
                    *(bf16x4v*)(vtb + ((long)(b * H_ + h) * D_ + d) * S_ + pos) = pk;
                } else {
                    long o = ((long)(b * H_ + h) * S_ + s) * D_ + d;
#pragma unroll
                    for (int r = 0; r < 4; ++r) {
                        float v = acc[i][j][r] + bv;
                        if (sel == 0) qb[o + (long)r * D_] = (bf16_t)(v * QSCALE);
                        else          kb[o + (long)r * D_] = (bf16_t)v;
                    }
                }
            } else {
#pragma unroll
                for (int r = 0; r < 4; ++r)
                    outf[(long)(mbase + r) * 768 + n] = acc[i][j][r] + bv;
            }
        }
    }
}

// ---------- attention: swapped QK^T, frozen-m softmax, in-register P ----------
// 4 waves x 32 q (two 16-row halves sharing every K/V LDS read), KVBLK=64,
// triple-buffered K/V with TWO-DEEP prefetch: body(t) = vmcnt(t's loads, issued
// two bodies ago) -> barrier -> STAGE(t+2) -> compute. One barrier per tile.
__global__ __launch_bounds__(256, 3)
void k_attn(const bf16_t* __restrict__ q, const bf16_t* __restrict__ k,
            const bf16_t* __restrict__ vt, bf16_t* __restrict__ ao) {
    __shared__ bf16_t Ksh[3][4096];   // [key][d], 128B rows, 3-bit chunk XOR
    __shared__ bf16_t Vsh[3][4096];   // [d][pos], 128B rows, 3-bit chunk XOR
    int bid = blockIdx.x;
    bid = (bid & 7) * 96 + (bid >> 3);    // XCD-aware swizzle (768 = 8*96)
    int bh = bid >> 5, qt = bid & 31;
    int q0 = qt * 128;
    int b = bh / H_, h = bh % H_;
    int t = threadIdx.x, lane = t & 63, wid = t >> 6;
    int l15 = lane & 15, l4 = lane >> 4;

    const bf16_t* qp = q + (long)bh * S_ * D_;
    const bf16_t* kp = k + (long)bh * S_ * D_;
    const bf16_t* vp = vt + (long)bh * D_ * S_;
    int wq = q0 + wid * 32;              // this wave's 32 q-rows (2 halves of 16)

    // Q fragments per half (B-operand: col=q=l15, contraction d-chunk 8*l4)
    bf16x8 qf[2][2];
#pragma unroll
    for (int g = 0; g < 2; ++g) {
        int row = wq + g * 16 + l15;
        qf[g][0] = *(const bf16x8*)(qp + (long)row * 64 + 8 * l4);
        qf[g][1] = *(const bf16x8*)(qp + (long)row * 64 + 32 + 8 * l4);
    }

    // LDS fragment addressing: 2 VGPR bases + compile-time immediates
    int sw = (l15 & 7) << 4;
    int a0 = l15 * 128 + ((16 * l4) ^ sw);
    int a1 = a0 ^ 64;

    f32x4 o[2][4], osum[2];
    f32x4 mneg4[2];
#pragma unroll
    for (int g = 0; g < 2; ++g) {
        osum[g] = f32x4{0.f, 0.f, 0.f, 0.f};
        mneg4[g] = f32x4{0.f, 0.f, 0.f, 0.f};
#pragma unroll
        for (int ns = 0; ns < 4; ++ns) o[g][ns] = f32x4{0.f, 0.f, 0.f, 0.f};
    }

    bf16x8 onesB;
#pragma unroll
    for (int j = 0; j < 8; ++j) onesB[j] = (bf16_t)1.0f;

    // staging: 256 threads x (2 K-chunks + 2 V-chunks); linear LDS dest, pre-swizzled src
    int i2b = t + 256;
    int rowA = t >> 3, rowB = i2b >> 3;
    int part = t & 7;
    int koffA = rowA * 64 + 8 * (part ^ (rowA & 7));
    int koffB = rowB * 64 + 8 * (part ^ (rowB & 7));
    int voffA = rowA * S_ + 8 * (part ^ (rowA & 7));
    int voffB = rowB * S_ + 8 * (part ^ (rowB & 7));
    int qt2 = 2 * qt;
    int qg0 = wq + l15;       // g=0 q-row of this lane
    int qg1 = qg0 + 16;       // g=1

    auto NK = [&](int i) { return i < qt2 ? i : i + 2; };

    auto STAGE = [&](int kts, auto bufc) {
        constexpr int buf = decltype(bufc)::v;
        char* Kd = (char*)Ksh + buf * 8192 + t * 16;
        char* Vd = (char*)Vsh + buf * 8192 + t * 16;
        long ko = (long)kts << 12;
        int vo = kts << 6;
        gload_lds16(kp + ko + koffA, Kd);
        gload_lds16(kp + ko + koffB, Kd + 4096);
        gload_lds16(vp + vo + voffA, Vd);
        gload_lds16(vp + vo + voffB, Vd + 4096);
    };

    // QK for both halves, each K fragment read ONCE
    auto QK = [&](auto curc, f32x4 (*s)[4], f32x4 ci0, f32x4 ci1) {
        constexpr int cur = decltype(curc)::v;
        const char* KL = (const char*)Ksh + cur * 8192;
#pragma unroll
        for (int ks = 0; ks < 4; ++ks) {
            bf16x8 kf0 = *(const bf16x8*)(KL + a0 + ks * 2048);
            bf16x8 kf1 = *(const bf16x8*)(KL + a1 + ks * 2048);
            s[0][ks] = __builtin_amdgcn_mfma_f32_16x16x32_bf16(kf0, qf[0][0], ci0, 0, 0, 0);
            s[1][ks] = __builtin_amdgcn_mfma_f32_16x16x32_bf16(kf0, qf[1][0], ci1, 0, 0, 0);
            s[0][ks] = __builtin_amdgcn_mfma_f32_16x16x32_bf16(kf1, qf[0][1], s[0][ks], 0, 0, 0);
            s[1][ks] = __builtin_amdgcn_mfma_f32_16x16x32_bf16(kf1, qf[1][1], s[1][ks], 0, 0, 0);
        }
    };

    auto MASK = [&](int kt, f32x4 (*s)[4]) {
        int k0 = kt << 6;
#pragma unroll
        for (int ks = 0; ks < 4; ++ks) {
            int kb_ = k0 + ks * 16 + l4 * 4;
#pragma unroll
            for (int r = 0; r < 4; ++r) {
                int d0 = qg0 - (kb_ + r); int ad0 = d0 < 0 ? -d0 : d0;
                if (ad0 <= WINDOW_) s[0][ks][r] = -1e30f;
                int d1 = qg1 - (kb_ + r); int ad1 = d1 < 0 ? -d1 : d1;
                if (ad1 <= WINDOW_) s[1][ks][r] = -1e30f;
            }
        }
    };

    // pack P (both halves) + rowsum + PV with each V fragment read ONCE
    auto TAIL = [&](auto curc, f32x4 (*s)[4]) {
        constexpr int cur = decltype(curc)::v;
        bf16x8 pa[2][2];
#pragma unroll
        for (int g = 0; g < 2; ++g)
#pragma unroll
            for (int c = 0; c < 2; ++c) {
                pa[g][c][0] = (bf16_t)s[g][2*c][0];   pa[g][c][1] = (bf16_t)s[g][2*c][1];
                pa[g][c][2] = (bf16_t)s[g][2*c][2];   pa[g][c][3] = (bf16_t)s[g][2*c][3];
                pa[g][c][4] = (bf16_t)s[g][2*c+1][0]; pa[g][c][5] = (bf16_t)s[g][2*c+1][1];
                pa[g][c][6] = (bf16_t)s[g][2*c+1][2]; pa[g][c][7] = (bf16_t)s[g][2*c+1][3];
            }
#pragma unroll
        for (int g = 0; g < 2; ++g) {
            osum[g] = __builtin_amdgcn_mfma_f32_16x16x32_bf16(pa[g][0], onesB, osum[g], 0, 0, 0);
            osum[g] = __builtin_amdgcn_mfma_f32_16x16x32_bf16(pa[g][1], onesB, osum[g], 0, 0, 0);
        }
        const char* VL = (const char*)Vsh + cur * 8192;
#pragma unroll
        for (int ns = 0; ns < 4; ++ns) {
            bf16x8 vf0 = *(const bf16x8*)(VL + a0 + ns * 2048);
            bf16x8 vf1 = *(const bf16x8*)(VL + a1 + ns * 2048);
            o[0][ns] = __builtin_amdgcn_mfma_f32_16x16x32_bf16(pa[0][0], vf0, o[0][ns], 0, 0, 0);
            o[1][ns] = __builtin_amdgcn_mfma_f32_16x16x32_bf16(pa[1][0], vf0, o[1][ns], 0, 0, 0);
            o[0][ns] = __builtin_amdgcn_mfma_f32_16x16x32_bf16(pa[0][1], vf1, o[0][ns], 0, 0, 0);
            o[1][ns] = __builtin_amdgcn_mfma_f32_16x16x32_bf16(pa[1][1], vf1, o[1][ns], 0, 0, 0);
        }
    };

    // body(t): vmcnt(t's loads, issued 2 bodies ago) -> barrier -> STAGE(t+2) -> compute(t)
    auto body = [&](int idx, auto curc) {
        if (idx < 61) {
            asm volatile("s_waitcnt vmcnt(4)" ::: "memory");
        } else {
            asm volatile("s_waitcnt vmcnt(0)" ::: "memory");
        }
        __builtin_amdgcn_s_barrier();
        if (idx + 2 < 62)
            STAGE(NK(idx + 2), IC<(decltype(curc)::v + 2) % 3>{});
        __builtin_amdgcn_sched_barrier(0);

        int kt = NK(idx);
        int dk = kt - qt2;
        f32x4 s[2][4];
        QK(curc, s, mneg4[0], mneg4[1]);      // C-init = -m: MFMA emits s_raw - m
        if (dk == -2 || dk == -1 || dk == 2 || dk == 3) MASK(kt, s);
#pragma unroll
        for (int g = 0; g < 2; ++g)
#pragma unroll
            for (int ks = 0; ks < 4; ++ks)
#pragma unroll
                for (int r = 0; r < 4; ++r)
                    s[g][ks][r] = fexp2(s[g][ks][r]);
        TAIL(curc, s);
    };

    // prologue: two tiles in flight before first compute
    STAGE(NK(0), IC<0>{});
    STAGE(NK(1), IC<1>{});

    // ---- first tile: establish frozen m (per half) ----
    {
        asm volatile("s_waitcnt vmcnt(4)" ::: "memory");   // own tile-0 loads landed
        __builtin_amdgcn_s_barrier();                      // all waves' tile-0 loads landed
        STAGE(NK(2), IC<2>{});
        __builtin_amdgcn_sched_barrier(0);

        int kt = NK(0);
        int dk = kt - qt2;
        f32x4 s[2][4];
        QK(IC<0>{}, s, f32x4{0.f,0.f,0.f,0.f}, f32x4{0.f,0.f,0.f,0.f});
        if (dk == -2 || dk == -1 || dk == 2 || dk == 3) MASK(kt, s);
#pragma unroll
        for (int g = 0; g < 2; ++g) {
            float lm = -1e30f;
#pragma unroll
            for (int ks = 0; ks < 4; ++ks) {
                float a = fmaxf(fmaxf(s[g][ks][0], s[g][ks][1]), fmaxf(s[g][ks][2], s[g][ks][3]));
                lm = fmaxf(lm, a);
            }
            lm = fmaxf(lm, __shfl_xor(lm, 16));
            lm = fmaxf(lm, __shfl_xor(lm, 32));
            float m_ = fmaxf(lm, 0.0f);   // guard: rows fully masked in first tile
            mneg4[g] = f32x4{-m_, -m_, -m_, -m_};
#pragma unroll
            for (int ks = 0; ks < 4; ++ks)
#pragma unroll
                for (int r = 0; r < 4; ++r)
                    s[g][ks][r] = fexp2(s[g][ks][r] - m_);
        }
        TAIL(IC<0>{}, s);
    }

    for (int i3 = 0; i3 < 20; ++i3) {
        body(3 * i3 + 1, IC<1>{});
        body(3 * i3 + 2, IC<2>{});
        body(3 * i3 + 3, IC<0>{});
    }
    body(61, IC<1>{});

    // finalize + write [B,S,E] bf16 (osum row-aligned with o)
#pragma unroll
    for (int g = 0; g < 2; ++g)
#pragma unroll
        for (int r = 0; r < 4; ++r) {
            float ir = 1.0f / osum[g][r];
            int srow2 = wq + g * 16 + l4 * 4 + r;
#pragma unroll
            for (int ns = 0; ns < 4; ++ns) {
                int e = h * 64 + ns * 16 + l15;
                ao[((long)b * S_ + srow2) * E_ + e] = (bf16_t)(o[g][ns][r] * ir);
            }
        }
}

extern "C" void kernel_launch(void* const* d_in, const int* in_sizes, int n_in,
                              void* d_out, int out_size, void* d_ws, size_t ws_size,
                              hipStream_t stream) {
    const float* x     = (const float*)d_in[0];
    const float* w_in  = (const float*)d_in[1];
    const float* b_in  = (const float*)d_in[2];
    const float* w_out = (const float*)d_in[3];
    const float* b_out = (const float*)d_in[4];
    float* out = (float*)d_out;

    char* ws = (char*)d_ws;
    bf16_t* xb  = (bf16_t*)(ws + 0);          // 12582912 (reused as attn-out)
    bf16_t* wib = (bf16_t*)(ws + 12582912);   // 3538944
    bf16_t* wob = (bf16_t*)(ws + 16121856);   // 1179648
    bf16_t* qb  = (bf16_t*)(ws + 17301504);   // 12582912
    bf16_t* kb  = (bf16_t*)(ws + 29884416);   // 12582912
    bf16_t* vtb = (bf16_t*)(ws + 42467328);   // 12582912
    bf16_t* ao  = xb;

    k_cvt<<<6144, 256, 0, stream>>>(x, xb, 6291456);
    k_cvt<<<1728, 256, 0, stream>>>(w_in, wib, 1769472);
    k_cvt<<<576, 256, 0, stream>>>(w_out, wob, 589824);

    // QKV projection: M=8192, N=2304, K=768 (v written pre-transposed + pre-permuted)
    k_gemm<0><<<64 * 18, 256, 0, stream>>>(xb, wib, b_in, qb, kb, vtb, nullptr,
                                           8192, 2304, 768, 64);
    k_attn<<<24 * 32, 256, 0, stream>>>(qb, kb, vtb, ao);
    // out projection: M=8192, N=768, K=768
    k_gemm<1><<<64 * 6, 256, 0, stream>>>(ao, wob, b_out, nullptr, nullptr, nullptr, out,
                                          8192, 768, 768, 64);
}